// Round 10
// baseline (314.142 us; speedup 1.0000x reference)
//
#include <hip/hip_runtime.h>
#include <math.h>

#define BB 16
#define TT 50
#define AA 3
#define CC 80
#define BA_ 85
#define HH 76
#define WW 76
#define SPAT (HH * WW)              // 5776
#define NPLANE (BB * AA)            // 48
#define CHUNK 512
#define NCHUNK ((SPAT + CHUNK - 1) / CHUNK)   // 12
#define NBLK (NPLANE * NCHUNK)      // 576

__constant__ float c_aw[3] = {1.25f, 2.0f, 4.125f};   // anchors / stride(=8)
__constant__ float c_ah[3] = {1.625f, 3.75f, 2.875f};

struct Rec { float tx, ty, tw, th; unsigned m0, m1, m2, pad; };   // 32 B

__device__ inline float wave_red(float v) {
    #pragma unroll
    for (int off = 32; off; off >>= 1) v += __shfl_down(v, off);
    return v;
}

// ---------------------------------------------------------------------------
// K1: per-batch build. state[b][a][cell]: 0=noobj, 1=cleared, 2+t=obj owner t.
// ---------------------------------------------------------------------------
__global__ __launch_bounds__(256) void k_build(const float* __restrict__ targets,
                                               unsigned char* __restrict__ state,
                                               Rec* __restrict__ recs) {
    const int b = blockIdx.x;
    const int tid = threadIdx.x;
    __shared__ int sh_valid[TT], sh_best[TT], sh_mcell[TT], sh_cls[TT];

    // zero this batch's state plane (3*5776 B = 1083 int4, 16B-aligned)
    int4* pl = (int4*)(state + (size_t)b * AA * SPAT);
    for (int k = tid; k < (AA * SPAT) / 16; k += 256) pl[k] = make_int4(0, 0, 0, 0);

    int valid = 0, best = 0, mcell = 0, icell = 0, ign = 0;
    float txv = 0.f, tyv = 0.f, twv = 0.f, thv = 0.f;
    if (tid < TT) {
        const float* tg = targets + ((size_t)b * TT + tid) * 5;
        float gx = tg[0] * WW, gy = tg[1] * HH;
        float gw = tg[2] * WW, gh = tg[3] * HH;
        int cls = (int)tg[4];
        valid = (gx + gy + gw + gh != 0.0f) ? 1 : 0;
        int gi = (int)floorf(gx); if (gi == 0) gi = 1;
        int gj = (int)floorf(gy); if (gj == 0) gj = 1;
        float bi = -1.f;
        #pragma unroll
        for (int a = 0; a < 3; ++a) {
            float inter = fminf(gw, c_aw[a]) * fminf(gh, c_ah[a]);
            float uni = gw * gh + 1e-16f + c_aw[a] * c_ah[a] - inter;
            float iou = inter / uni;
            if (iou > bi) { bi = iou; best = a; }     // first-wins argmax
            if (iou > 0.5f) ign |= 1 << a;
        }
        icell = gi * WW + gj;   // ignore-clear at noobj[b,:,gi,gj] -> H<-gi, W<-gj
        mcell = gj * WW + gi;   // main write at (b,best,gj,gi)     -> H<-gj, W<-gi
        txv = gx - (float)gi;
        tyv = gy - (float)gj;
        twv = logf(gw / c_aw[best] + 1e-16f);
        thv = logf(gh / c_ah[best] + 1e-16f);
        sh_valid[tid] = valid; sh_best[tid] = best;
        sh_mcell[tid] = mcell; sh_cls[tid] = cls;
    }
    __syncthreads();            // plane zeroed + sh arrays visible

    unsigned char* st = state + (size_t)b * AA * SPAT;
    if (tid < TT && valid) {    // phase A: cleared (value 1) — benign races
        #pragma unroll
        for (int a = 0; a < 3; ++a)
            if ((ign >> a) & 1) st[a * SPAT + icell] = 1;
        st[best * SPAT + mcell] = 1;
    }
    __syncthreads();            // all 1s land before owners overwrite

    if (tid < TT && valid) {    // phase B: owners write 2+t and their Rec
        bool owner = true;      // owner iff no LATER valid target hits same (cell,anchor)
        for (int t2 = tid + 1; t2 < TT; ++t2)
            if (sh_valid[t2] && sh_mcell[t2] == mcell && sh_best[t2] == best) {
                owner = false; break;
            }
        if (owner) {
            unsigned m0 = 0u, m1 = 0u, m2 = 0u;   // tcls union over ALL writers
            for (int t2 = 0; t2 < TT; ++t2)
                if (sh_valid[t2] && sh_mcell[t2] == mcell && sh_best[t2] == best) {
                    int c = sh_cls[t2];
                    if (c < 32) m0 |= 1u << c;
                    else if (c < 64) m1 |= 1u << (c - 32);
                    else m2 |= 1u << (c - 64);
                }
            Rec r; r.tx = txv; r.ty = tyv; r.tw = twv; r.th = thv;
            r.m0 = m0; r.m1 = m1; r.m2 = m2; r.pad = 0u;
            recs[b * TT + tid] = r;
            st[best * SPAT + mcell] = (unsigned char)(2 + tid);
        }
    }
}

// ---------------------------------------------------------------------------
// K2: dense sweep of ALL of pred (94 MB, coalesced float4, sequential pages).
// One block per (plane, 512-cell chunk); compute gated by the state byte.
// part[blk*6 + {mse,bo,bn,bc,no,cn}], written unconditionally.
// ---------------------------------------------------------------------------
__global__ __launch_bounds__(128) void k_dense(const float* __restrict__ pred,
                                               const unsigned char* __restrict__ state,
                                               const Rec* __restrict__ recs,
                                               float* __restrict__ part) {
    const int blk = blockIdx.x;
    const int p = blk / NCHUNK;              // b*AA + a
    const int chunk = blk - p * NCHUNK;
    const int b = p / AA;
    const int tid = threadIdx.x;

    __shared__ Rec lrec[TT];
    for (int k = tid; k < TT * 8; k += 128)  // 50 recs = 400 words
        ((unsigned*)lrec)[k] = ((const unsigned*)(recs + (size_t)b * TT))[k];
    __syncthreads();

    float s_mse = 0.f, s_bo = 0.f, s_bn = 0.f, s_bc = 0.f, s_no = 0.f, s_cn = 0.f;
    const int s0 = chunk * CHUNK + tid * 4;

    if (s0 < SPAT) {
        uchar4 s4 = *(const uchar4*)(state + (size_t)p * SPAT + s0);
        int st[4] = {s4.x, s4.y, s4.z, s4.w};
        const float* pb = pred + (size_t)p * BA_ * SPAT + s0;

        // channels 0..3: box MSE (obj cells only); count n_obj at c==0
        #pragma unroll
        for (int c = 0; c < 4; ++c) {
            float4 z4 = *(const float4*)(pb + (size_t)c * SPAT);
            float zz[4] = {z4.x, z4.y, z4.z, z4.w};
            #pragma unroll
            for (int k = 0; k < 4; ++k)
                if (st[k] >= 2) {
                    const Rec& r = lrec[st[k] - 2];
                    float tv = (&r.tx)[c];
                    float v = (c < 2) ? 1.f / (1.f + expf(-zz[k])) : zz[k];
                    s_mse += (v - tv) * (v - tv);
                    if (c == 0) s_no += 1.f;
                }
        }
        {   // channel 4: conf BCE (noobj: tconf=0; obj: tconf=1)
            float4 z4 = *(const float4*)(pb + (size_t)4 * SPAT);
            float zz[4] = {z4.x, z4.y, z4.z, z4.w};
            #pragma unroll
            for (int k = 0; k < 4; ++k) {
                float conf = 1.f / (1.f + expf(-zz[k]));
                if (st[k] == 0) {
                    s_cn += 1.f;
                    s_bn += -fmaxf(log1pf(-conf), -100.f);
                } else if (st[k] >= 2) {
                    s_bo += -fmaxf(logf(conf), -100.f);
                }
            }
        }
        // channels 5..84: class BCE (obj cells only). Loads are UNCONDITIONAL
        // (keep-alive asm) — dense sequential fetch is the whole point.
        bool anyobj = ((st[0] | st[1] | st[2] | st[3]) >= 2);
        #pragma unroll 8
        for (int c = 5; c < BA_; ++c) {
            float4 z4 = *(const float4*)(pb + (size_t)c * SPAT);
            asm volatile("" :: "v"(z4.x), "v"(z4.y), "v"(z4.z), "v"(z4.w));
            if (anyobj) {
                float zz[4] = {z4.x, z4.y, z4.z, z4.w};
                int ci = c - 5;
                #pragma unroll
                for (int k = 0; k < 4; ++k)
                    if (st[k] >= 2) {
                        const Rec& r = lrec[st[k] - 2];
                        unsigned wd = (&r.m0)[ci >> 5];
                        int tcv = (wd >> (ci & 31)) & 1;
                        float pr = 1.f / (1.f + expf(-zz[k]));
                        s_bc += tcv ? -fmaxf(logf(pr), -100.f)
                                    : -fmaxf(log1pf(-pr), -100.f);
                    }
            }
        }
    }

    s_mse = wave_red(s_mse); s_bo = wave_red(s_bo); s_bn = wave_red(s_bn);
    s_bc  = wave_red(s_bc);  s_no = wave_red(s_no); s_cn = wave_red(s_cn);
    __shared__ float red[2][6];
    int wv = tid >> 6, ln = tid & 63;
    if (ln == 0) {
        red[wv][0] = s_mse; red[wv][1] = s_bo; red[wv][2] = s_bn;
        red[wv][3] = s_bc;  red[wv][4] = s_no; red[wv][5] = s_cn;
    }
    __syncthreads();
    if (tid == 0) {
        #pragma unroll
        for (int k = 0; k < 6; ++k)
            part[blk * 6 + k] = red[0][k] + red[1][k];
    }
}

// ---------------------------------------------------------------------------
// K3: reduce NBLK partials, final loss.
// ---------------------------------------------------------------------------
__global__ __launch_bounds__(256) void k_final(const float* __restrict__ part,
                                               float* __restrict__ out) {
    const int tid = threadIdx.x;
    float v[6] = {0.f, 0.f, 0.f, 0.f, 0.f, 0.f};
    for (int i = tid; i < NBLK; i += 256) {
        #pragma unroll
        for (int k = 0; k < 6; ++k) v[k] += part[i * 6 + k];
    }
    #pragma unroll
    for (int k = 0; k < 6; ++k) v[k] = wave_red(v[k]);
    __shared__ float red[4][6];
    int wv = tid >> 6, ln = tid & 63;
    if (ln == 0) {
        #pragma unroll
        for (int k = 0; k < 6; ++k) red[wv][k] = v[k];
    }
    __syncthreads();
    if (tid == 0) {
        float m[6];
        #pragma unroll
        for (int k = 0; k < 6; ++k)
            m[k] = red[0][k] + red[1][k] + red[2][k] + red[3][k];
        float n_obj   = fmaxf(m[4], 1.f);
        float n_noobj = fmaxf(m[5], 1.f);
        out[0] = m[0] / n_obj                      // x+y+w+h MSE
               + m[1] / n_obj                      // OBJ_SCALE * conf-obj BCE
               + 100.f * (m[2] / n_noobj)          // NOOBJ_SCALE * conf-noobj BCE
               + m[3] / (n_obj * (float)CC);       // class BCE
    }
}

extern "C" void kernel_launch(void* const* d_in, const int* in_sizes, int n_in,
                              void* d_out, int out_size, void* d_ws, size_t ws_size,
                              hipStream_t stream) {
    const float* pred    = (const float*)d_in[0];
    const float* targets = (const float*)d_in[1];
    float* out = (float*)d_out;
    char* ws = (char*)d_ws;

    // ws: [0, 25600) recs (16*50*32B) | [25600, 302848) state (16*3*5776 B) |
    //     [302848, +13824) part (576*6 f32).  All consumed bytes are written
    //     each launch before being read -> no memset node needed.
    Rec*           recs  = (Rec*)ws;
    unsigned char* state = (unsigned char*)(ws + 25600);
    float*         part  = (float*)(ws + 302848);

    k_build<<<BB, 256, 0, stream>>>(targets, state, recs);
    k_dense<<<NBLK, 128, 0, stream>>>(pred, state, recs, part);
    k_final<<<1, 256, 0, stream>>>(part, out);
}

// Round 13
// 161.347 us; speedup vs baseline: 1.9470x; 1.9470x over previous
//
#include <hip/hip_runtime.h>
#include <math.h>

#define BB 16
#define TT 50
#define AA 3
#define CC 80
#define BA_ 85
#define HH 76
#define WW 76
#define SPAT (HH * WW)              // 5776
#define NPLANE (BB * AA)            // 48
#define NQ (SPAT / 4)               // 1444 float4 per channel row
#define P4 (BA_ * NQ)               // 122740 float4 per (b,a) plane
#define TOTAL4 (NPLANE * P4)        // 5,891,520 float4 in pred
#define GRID 2048                   // 8 blocks/CU on 256 CUs
#define NTH 256

__constant__ float c_aw[3] = {1.25f, 2.0f, 4.125f};   // anchors / stride(=8)
__constant__ float c_ah[3] = {1.625f, 3.75f, 2.875f};

struct Rec { float tx, ty, tw, th; unsigned m0, m1, m2, pad; };   // 32 B

__device__ inline float wave_red(float v) {
    #pragma unroll
    for (int off = 32; off; off >>= 1) v += __shfl_down(v, off);
    return v;
}

// ---------------------------------------------------------------------------
// K1: per-batch build. state[b][a][cell]: 0=noobj, 1=cleared, 2+t=obj owner t.
// ---------------------------------------------------------------------------
__global__ __launch_bounds__(256) void k_build(const float* __restrict__ targets,
                                               unsigned char* __restrict__ state,
                                               Rec* __restrict__ recs) {
    const int b = blockIdx.x;
    const int tid = threadIdx.x;
    __shared__ int sh_valid[TT], sh_best[TT], sh_mcell[TT], sh_cls[TT];

    // zero this batch's state plane (3*5776 B = 1083 int4, 16B-aligned)
    int4* pl = (int4*)(state + (size_t)b * AA * SPAT);
    for (int k = tid; k < (AA * SPAT) / 16; k += 256) pl[k] = make_int4(0, 0, 0, 0);

    int valid = 0, best = 0, mcell = 0, icell = 0, ign = 0;
    float txv = 0.f, tyv = 0.f, twv = 0.f, thv = 0.f;
    if (tid < TT) {
        const float* tg = targets + ((size_t)b * TT + tid) * 5;
        float gx = tg[0] * WW, gy = tg[1] * HH;
        float gw = tg[2] * WW, gh = tg[3] * HH;
        int cls = (int)tg[4];
        valid = (gx + gy + gw + gh != 0.0f) ? 1 : 0;
        int gi = (int)floorf(gx); if (gi == 0) gi = 1;
        int gj = (int)floorf(gy); if (gj == 0) gj = 1;
        float bi = -1.f;
        #pragma unroll
        for (int a = 0; a < 3; ++a) {
            float inter = fminf(gw, c_aw[a]) * fminf(gh, c_ah[a]);
            float uni = gw * gh + 1e-16f + c_aw[a] * c_ah[a] - inter;
            float iou = inter / uni;
            if (iou > bi) { bi = iou; best = a; }     // first-wins argmax
            if (iou > 0.5f) ign |= 1 << a;
        }
        icell = gi * WW + gj;   // ignore-clear at noobj[b,:,gi,gj] -> H<-gi, W<-gj
        mcell = gj * WW + gi;   // main write at (b,best,gj,gi)     -> H<-gj, W<-gi
        txv = gx - (float)gi;
        tyv = gy - (float)gj;
        twv = logf(gw / c_aw[best] + 1e-16f);
        thv = logf(gh / c_ah[best] + 1e-16f);
        sh_valid[tid] = valid; sh_best[tid] = best;
        sh_mcell[tid] = mcell; sh_cls[tid] = cls;
    }
    __syncthreads();            // plane zeroed + sh arrays visible

    unsigned char* st = state + (size_t)b * AA * SPAT;
    if (tid < TT && valid) {    // phase A: cleared (value 1) — benign races
        #pragma unroll
        for (int a = 0; a < 3; ++a)
            if ((ign >> a) & 1) st[a * SPAT + icell] = 1;
        st[best * SPAT + mcell] = 1;
    }
    __syncthreads();            // all 1s land before owners overwrite

    if (tid < TT && valid) {    // phase B: owners write 2+t and their Rec
        bool owner = true;      // owner iff no LATER valid target hits same (cell,anchor)
        for (int t2 = tid + 1; t2 < TT; ++t2)
            if (sh_valid[t2] && sh_mcell[t2] == mcell && sh_best[t2] == best) {
                owner = false; break;
            }
        if (owner) {
            unsigned m0 = 0u, m1 = 0u, m2 = 0u;   // tcls union over ALL writers
            for (int t2 = 0; t2 < TT; ++t2)
                if (sh_valid[t2] && sh_mcell[t2] == mcell && sh_best[t2] == best) {
                    int c = sh_cls[t2];
                    if (c < 32) m0 |= 1u << c;
                    else if (c < 64) m1 |= 1u << (c - 32);
                    else m2 |= 1u << (c - 64);
                }
            Rec r; r.tx = txv; r.ty = tyv; r.tw = twv; r.th = thv;
            r.m0 = m0; r.m1 = m1; r.m2 = m2; r.pad = 0u;
            recs[b * TT + tid] = r;
            st[best * SPAT + mcell] = (unsigned char)(2 + tid);
        }
    }
}

// ---------------------------------------------------------------------------
// K2: FLAT grid-stride dense sweep of pred (94 MB coalesced float4).
// 2048x256 = 8 blocks/CU, 8 waves/SIMD -> TLP hides HBM/L3 latency.
// f -> (plane p, channel c, quad q); compute gated by per-cell state byte;
// recs fetched from global only on rare obj lanes (L2-resident, 25 KB).
// ---------------------------------------------------------------------------
__global__ __launch_bounds__(256) void k_dense(const float* __restrict__ pred,
                                               const unsigned char* __restrict__ state,
                                               const Rec* __restrict__ recs,
                                               float* __restrict__ part) {
    const int tid = blockIdx.x * NTH + threadIdx.x;
    float s_mse = 0.f, s_bo = 0.f, s_bn = 0.f, s_bc = 0.f, s_no = 0.f, s_cn = 0.f;

    for (int f = tid; f < TOTAL4; f += GRID * NTH) {
        float4 z4 = *reinterpret_cast<const float4*>(pred + (size_t)f * 4);
        asm volatile("" :: "v"(z4.x), "v"(z4.y), "v"(z4.z), "v"(z4.w));  // pin load

        int p = f / P4;                 // plane = b*AA + a
        int r = f - p * P4;
        int c = r / NQ;                 // channel 0..84
        int s0 = (r - c * NQ) * 4;      // spatial cell base
        uchar4 s4 = *reinterpret_cast<const uchar4*>(state + (size_t)p * SPAT + s0);
        int st[4] = {s4.x, s4.y, s4.z, s4.w};
        float zz[4] = {z4.x, z4.y, z4.z, z4.w};
        int b = p / AA;

        if (c == 4) {                   // conf BCE: every cell is noobj or obj-or-cleared
            #pragma unroll
            for (int k = 0; k < 4; ++k) {
                float conf = 1.f / (1.f + expf(-zz[k]));
                if (st[k] == 0) {
                    s_cn += 1.f;
                    s_bn += -fmaxf(log1pf(-conf), -100.f);   // tconf=0
                } else if (st[k] >= 2) {
                    s_bo += -fmaxf(logf(conf), -100.f);      // tconf=1
                }
            }
        } else if (c < 4) {             // box MSE, obj cells only; n_obj at c==0
            #pragma unroll
            for (int k = 0; k < 4; ++k)
                if (st[k] >= 2) {
                    const Rec rr = recs[b * TT + st[k] - 2];
                    float tv = (c == 0) ? rr.tx : (c == 1) ? rr.ty
                             : (c == 2) ? rr.tw : rr.th;
                    float v = (c < 2) ? 1.f / (1.f + expf(-zz[k])) : zz[k];
                    s_mse += (v - tv) * (v - tv);
                    if (c == 0) s_no += 1.f;
                }
        } else {                        // class BCE, obj cells only
            int ci = c - 5;
            #pragma unroll
            for (int k = 0; k < 4; ++k)
                if (st[k] >= 2) {
                    const Rec rr = recs[b * TT + st[k] - 2];
                    unsigned wd = (ci < 32) ? rr.m0 : (ci < 64) ? rr.m1 : rr.m2;
                    int tcv = (wd >> (ci & 31)) & 1;
                    float pr = 1.f / (1.f + expf(-zz[k]));
                    s_bc += tcv ? -fmaxf(logf(pr), -100.f)
                                : -fmaxf(log1pf(-pr), -100.f);
                }
        }
    }

    s_mse = wave_red(s_mse); s_bo = wave_red(s_bo); s_bn = wave_red(s_bn);
    s_bc  = wave_red(s_bc);  s_no = wave_red(s_no); s_cn = wave_red(s_cn);
    __shared__ float red[4][6];
    int wv = threadIdx.x >> 6, ln = threadIdx.x & 63;
    if (ln == 0) {
        red[wv][0] = s_mse; red[wv][1] = s_bo; red[wv][2] = s_bn;
        red[wv][3] = s_bc;  red[wv][4] = s_no; red[wv][5] = s_cn;
    }
    __syncthreads();
    if (threadIdx.x == 0) {
        #pragma unroll
        for (int k = 0; k < 6; ++k)
            part[blockIdx.x * 6 + k] =
                red[0][k] + red[1][k] + red[2][k] + red[3][k];
    }
}

// ---------------------------------------------------------------------------
// K3: reduce GRID partials, final loss.
// ---------------------------------------------------------------------------
__global__ __launch_bounds__(256) void k_final(const float* __restrict__ part,
                                               float* __restrict__ out) {
    const int tid = threadIdx.x;
    float v[6] = {0.f, 0.f, 0.f, 0.f, 0.f, 0.f};
    for (int i = tid; i < GRID; i += 256) {
        #pragma unroll
        for (int k = 0; k < 6; ++k) v[k] += part[i * 6 + k];
    }
    #pragma unroll
    for (int k = 0; k < 6; ++k) v[k] = wave_red(v[k]);
    __shared__ float red[4][6];
    int wv = tid >> 6, ln = tid & 63;
    if (ln == 0) {
        #pragma unroll
        for (int k = 0; k < 6; ++k) red[wv][k] = v[k];
    }
    __syncthreads();
    if (tid == 0) {
        float m[6];
        #pragma unroll
        for (int k = 0; k < 6; ++k)
            m[k] = red[0][k] + red[1][k] + red[2][k] + red[3][k];
        float n_obj   = fmaxf(m[4], 1.f);
        float n_noobj = fmaxf(m[5], 1.f);
        out[0] = m[0] / n_obj                      // x+y+w+h MSE
               + m[1] / n_obj                      // OBJ_SCALE * conf-obj BCE
               + 100.f * (m[2] / n_noobj)          // NOOBJ_SCALE * conf-noobj BCE
               + m[3] / (n_obj * (float)CC);       // class BCE
    }
}

extern "C" void kernel_launch(void* const* d_in, const int* in_sizes, int n_in,
                              void* d_out, int out_size, void* d_ws, size_t ws_size,
                              hipStream_t stream) {
    const float* pred    = (const float*)d_in[0];
    const float* targets = (const float*)d_in[1];
    float* out = (float*)d_out;
    char* ws = (char*)d_ws;

    // ws: [0, 25600) recs (16*50*32B) | [25600, 302848) state (16*3*5776 B) |
    //     [302848, +49152) part (2048*6 f32).  Every consumed byte is written
    //     each launch before being read -> no memset node needed.
    Rec*           recs  = (Rec*)ws;
    unsigned char* state = (unsigned char*)(ws + 25600);
    float*         part  = (float*)(ws + 302848);

    k_build<<<BB, 256, 0, stream>>>(targets, state, recs);
    k_dense<<<GRID, NTH, 0, stream>>>(pred, state, recs, part);
    k_final<<<1, 256, 0, stream>>>(part, out);
}

// Round 14
// 139.484 us; speedup vs baseline: 2.2522x; 1.1567x over previous
//
#include <hip/hip_runtime.h>
#include <math.h>

#define BB 16
#define TT 50
#define AA 3
#define CC 80
#define BA_ 85
#define HH 76
#define WW 76
#define SPAT (HH * WW)              // 5776
#define NQ (SPAT / 4)               // 1444 float4 per channel row
#define NCONF4 (BB * AA * NQ)       // 69312 float4 of conf channel
#define NCONFB ((NCONF4 + 255) / 256)   // 271 conf blocks
#define NOBJB (BB * TT / 4)         // 200 gather blocks (4 recs each)
#define GRID2 (NCONFB + NOBJB)      // 471

__constant__ float c_aw[3] = {1.25f, 2.0f, 4.125f};   // anchors / stride(=8)
__constant__ float c_ah[3] = {1.625f, 3.75f, 2.875f};

struct Rec { int base; float tx, ty, tw, th; unsigned m0, m1, m2; };   // 32 B

__device__ inline float wave_red(float v) {
    #pragma unroll
    for (int off = 32; off; off >>= 1) v += __shfl_down(v, off);
    return v;
}

// ---------------------------------------------------------------------------
// K1: per-batch build. state[b][a][cell]: 0=noobj, 1=cleared/obj.
// recs: ALL 800 slots written; base = pred offset of owned cell, or -1.
// ---------------------------------------------------------------------------
__global__ __launch_bounds__(256) void k_build(const float* __restrict__ targets,
                                               unsigned char* __restrict__ state,
                                               Rec* __restrict__ recs) {
    const int b = blockIdx.x;
    const int tid = threadIdx.x;
    __shared__ int sh_valid[TT], sh_best[TT], sh_mcell[TT], sh_cls[TT];

    // zero this batch's state plane (3*5776 B, 16B-aligned)
    int4* pl = (int4*)(state + (size_t)b * AA * SPAT);
    for (int k = tid; k < (AA * SPAT) / 16; k += 256) pl[k] = make_int4(0, 0, 0, 0);

    int valid = 0, best = 0, mcell = 0, icell = 0, ign = 0;
    float txv = 0.f, tyv = 0.f, twv = 0.f, thv = 0.f;
    if (tid < TT) {
        const float* tg = targets + ((size_t)b * TT + tid) * 5;
        float gx = tg[0] * WW, gy = tg[1] * HH;
        float gw = tg[2] * WW, gh = tg[3] * HH;
        int cls = (int)tg[4];
        valid = (gx + gy + gw + gh != 0.0f) ? 1 : 0;
        int gi = (int)floorf(gx); if (gi == 0) gi = 1;
        int gj = (int)floorf(gy); if (gj == 0) gj = 1;
        float bi = -1.f;
        #pragma unroll
        for (int a = 0; a < 3; ++a) {
            float inter = fminf(gw, c_aw[a]) * fminf(gh, c_ah[a]);
            float uni = gw * gh + 1e-16f + c_aw[a] * c_ah[a] - inter;
            float iou = inter / uni;
            if (iou > bi) { bi = iou; best = a; }     // first-wins argmax
            if (iou > 0.5f) ign |= 1 << a;
        }
        icell = gi * WW + gj;   // ignore-clear at noobj[b,:,gi,gj] -> H<-gi, W<-gj
        mcell = gj * WW + gi;   // main write at (b,best,gj,gi)     -> H<-gj, W<-gi
        txv = gx - (float)gi;
        tyv = gy - (float)gj;
        twv = logf(gw / c_aw[best] + 1e-16f);
        thv = logf(gh / c_ah[best] + 1e-16f);
        sh_valid[tid] = valid; sh_best[tid] = best;
        sh_mcell[tid] = mcell; sh_cls[tid] = cls;
    }
    __syncthreads();            // plane zeroed + sh arrays visible

    unsigned char* st = state + (size_t)b * AA * SPAT;
    if (tid < TT && valid) {    // cleared marks (value 1) — benign races
        #pragma unroll
        for (int a = 0; a < 3; ++a)
            if ((ign >> a) & 1) st[a * SPAT + icell] = 1;
        st[best * SPAT + mcell] = 1;   // obj cell also leaves noobj
    }

    if (tid < TT) {             // write EVERY rec slot (holes get base=-1)
        Rec r; r.base = -1;
        r.tx = txv; r.ty = tyv; r.tw = twv; r.th = thv;
        r.m0 = 0u; r.m1 = 0u; r.m2 = 0u;
        if (valid) {
            bool owner = true;  // owner iff no LATER valid target hits same (cell,anchor)
            for (int t2 = tid + 1; t2 < TT; ++t2)
                if (sh_valid[t2] && sh_mcell[t2] == mcell && sh_best[t2] == best) {
                    owner = false; break;
                }
            if (owner) {
                unsigned m0 = 0u, m1 = 0u, m2 = 0u;   // tcls union over ALL writers
                for (int t2 = 0; t2 < TT; ++t2)
                    if (sh_valid[t2] && sh_mcell[t2] == mcell && sh_best[t2] == best) {
                        int c = sh_cls[t2];
                        if (c < 32) m0 |= 1u << c;
                        else if (c < 64) m1 |= 1u << (c - 32);
                        else m2 |= 1u << (c - 64);
                    }
                r.base = ((b * AA + best) * BA_) * SPAT + mcell;
                r.m0 = m0; r.m1 = m1; r.m2 = m2;
            }
        }
        recs[b * TT + tid] = r;
    }
}

// ---------------------------------------------------------------------------
// K2: fused conf-noobj pass + obj gather.
//   blocks [0, NCONFB): dense float4 sweep of conf channel (1.1 MB), st==0.
//   blocks [NCONFB, GRID2): 4 waves x 1 rec; lane = channel (2 wave-loads).
// Per-block partials -> part[blk*6], written unconditionally; no atomics.
// ---------------------------------------------------------------------------
__global__ __launch_bounds__(256) void k_sweep(const float* __restrict__ pred,
                                               const unsigned char* __restrict__ state,
                                               const Rec* __restrict__ recs,
                                               float* __restrict__ part) {
    const int blk = blockIdx.x;
    const int tid = threadIdx.x;
    float s_mse = 0.f, s_bo = 0.f, s_bn = 0.f, s_bc = 0.f, s_no = 0.f, s_cn = 0.f;

    if (blk < NCONFB) {
        int f = blk * 256 + tid;
        if (f < NCONF4) {
            int p = f / NQ;                  // plane = b*AA + a
            int q = f - p * NQ;
            float4 z4 = *reinterpret_cast<const float4*>(
                pred + ((size_t)p * BA_ + 4) * SPAT + q * 4);
            uchar4 s4 = *reinterpret_cast<const uchar4*>(
                state + (size_t)p * SPAT + q * 4);
            int st[4] = {s4.x, s4.y, s4.z, s4.w};
            float zz[4] = {z4.x, z4.y, z4.z, z4.w};
            #pragma unroll
            for (int k = 0; k < 4; ++k)
                if (st[k] == 0) {            // noobj cell, tconf = 0
                    float conf = 1.f / (1.f + expf(-zz[k]));
                    s_cn += 1.f;
                    s_bn += -fmaxf(log1pf(-conf), -100.f);
                }
        }
    } else {
        int r = (blk - NCONFB) * 4 + (tid >> 6);   // rec slot 0..799
        int lane = tid & 63;
        Rec rr = recs[r];
        if (rr.base >= 0) {
            // issue both scattered loads up front (independent)
            float z  = pred[(size_t)rr.base + (size_t)lane * SPAT];
            float z2 = 0.f;
            if (lane < BA_ - 64)
                z2 = pred[(size_t)rr.base + (size_t)(64 + lane) * SPAT];

            if (lane == 0) {
                float x = 1.f / (1.f + expf(-z));
                s_mse += (x - rr.tx) * (x - rr.tx);
                s_no += 1.f;                          // n_obj per owned cell
            } else if (lane == 1) {
                float y = 1.f / (1.f + expf(-z));
                s_mse += (y - rr.ty) * (y - rr.ty);
            } else if (lane == 2) {
                s_mse += (z - rr.tw) * (z - rr.tw);
            } else if (lane == 3) {
                s_mse += (z - rr.th) * (z - rr.th);
            } else if (lane == 4) {
                float cf = 1.f / (1.f + expf(-z));
                s_bo += -fmaxf(logf(cf), -100.f);     // tconf = 1
            } else {                                   // class ci = lane-5 in [0,58]
                int ci = lane - 5;
                unsigned wd = (ci < 32) ? rr.m0 : rr.m1;
                int tcv = (wd >> (ci & 31)) & 1;
                float p = 1.f / (1.f + expf(-z));
                s_bc += tcv ? -fmaxf(logf(p), -100.f)
                            : -fmaxf(log1pf(-p), -100.f);
            }
            if (lane < BA_ - 64) {                     // ci = 59+lane in [59,79]
                int ci = 59 + lane;
                unsigned wd = (ci < 64) ? rr.m1 : rr.m2;
                int tcv = (wd >> (ci & 31)) & 1;
                float p = 1.f / (1.f + expf(-z2));
                s_bc += tcv ? -fmaxf(logf(p), -100.f)
                            : -fmaxf(log1pf(-p), -100.f);
            }
        }
    }

    s_mse = wave_red(s_mse); s_bo = wave_red(s_bo); s_bn = wave_red(s_bn);
    s_bc  = wave_red(s_bc);  s_no = wave_red(s_no); s_cn = wave_red(s_cn);
    __shared__ float red[4][6];
    int wv = tid >> 6, ln = tid & 63;
    if (ln == 0) {
        red[wv][0] = s_mse; red[wv][1] = s_bo; red[wv][2] = s_bn;
        red[wv][3] = s_bc;  red[wv][4] = s_no; red[wv][5] = s_cn;
    }
    __syncthreads();
    if (tid == 0) {
        #pragma unroll
        for (int k = 0; k < 6; ++k)
            part[blk * 6 + k] = red[0][k] + red[1][k] + red[2][k] + red[3][k];
    }
}

// ---------------------------------------------------------------------------
// K3: reduce GRID2 partials, final loss.
// ---------------------------------------------------------------------------
__global__ __launch_bounds__(256) void k_final(const float* __restrict__ part,
                                               float* __restrict__ out) {
    const int tid = threadIdx.x;
    float v[6] = {0.f, 0.f, 0.f, 0.f, 0.f, 0.f};
    for (int i = tid; i < GRID2; i += 256) {
        #pragma unroll
        for (int k = 0; k < 6; ++k) v[k] += part[i * 6 + k];
    }
    #pragma unroll
    for (int k = 0; k < 6; ++k) v[k] = wave_red(v[k]);
    __shared__ float red[4][6];
    int wv = tid >> 6, ln = tid & 63;
    if (ln == 0) {
        #pragma unroll
        for (int k = 0; k < 6; ++k) red[wv][k] = v[k];
    }
    __syncthreads();
    if (tid == 0) {
        float m[6];
        #pragma unroll
        for (int k = 0; k < 6; ++k)
            m[k] = red[0][k] + red[1][k] + red[2][k] + red[3][k];
        float n_obj   = fmaxf(m[4], 1.f);
        float n_noobj = fmaxf(m[5], 1.f);
        out[0] = m[0] / n_obj                      // x+y+w+h MSE
               + m[1] / n_obj                      // OBJ_SCALE * conf-obj BCE
               + 100.f * (m[2] / n_noobj)          // NOOBJ_SCALE * conf-noobj BCE
               + m[3] / (n_obj * (float)CC);       // class BCE
    }
}

extern "C" void kernel_launch(void* const* d_in, const int* in_sizes, int n_in,
                              void* d_out, int out_size, void* d_ws, size_t ws_size,
                              hipStream_t stream) {
    const float* pred    = (const float*)d_in[0];
    const float* targets = (const float*)d_in[1];
    float* out = (float*)d_out;
    char* ws = (char*)d_ws;

    // ws: [0, 25600) recs (800*32B) | [25600, 302848) state (16*3*5776 B) |
    //     [302848, +11304) part (471*6 f32). Every consumed byte is written
    //     each launch before being read -> no memset node needed.
    Rec*           recs  = (Rec*)ws;
    unsigned char* state = (unsigned char*)(ws + 25600);
    float*         part  = (float*)(ws + 302848);

    k_build<<<BB, 256, 0, stream>>>(targets, state, recs);
    k_sweep<<<GRID2, 256, 0, stream>>>(pred, state, recs, part);
    k_final<<<1, 256, 0, stream>>>(part, out);
}